// Round 7
// baseline (597.187 us; speedup 1.0000x reference)
//
#include <hip/hip_runtime.h>

typedef unsigned short u16;
typedef __attribute__((ext_vector_type(8))) _Float16 f16x8;
typedef __attribute__((ext_vector_type(4))) float f32x4;

#define S_CTX 2048
#define DMODEL 2048

#define WAITVM(N) asm volatile("s_waitcnt vmcnt(" #N ")" ::: "memory")
#define SBAR() __builtin_amdgcn_s_barrier()

__device__ __forceinline__ u16 f2h(float f) {
  _Float16 h = (_Float16)f; u16 u; __builtin_memcpy(&u, &h, 2); return u;
}
__device__ __forceinline__ float h2f(u16 u) {
  _Float16 h; __builtin_memcpy(&h, &u, 2); return (float)h;
}
__device__ __forceinline__ void gload16(const u16* g, u16* l) {
  __builtin_amdgcn_global_load_lds(
      (const __attribute__((address_space(1))) unsigned int*)g,
      (__attribute__((address_space(3))) unsigned int*)l, 16, 0, 0);
}

// One fused split pass. x -> fp16 pair (no scale). Wq,Wk -> fp16 pair (x64).
// Wv,Wo -> fp16 single (x64). Scales folded out downstream (q-prescale, /4096).
__global__ void split_all(const float* __restrict__ x, const float* __restrict__ Wq,
                          const float* __restrict__ Wk, const float* __restrict__ Wv,
                          const float* __restrict__ Wo,
                          u16* xh, u16* xl, u16* Wqh, u16* Wql,
                          u16* Wkh, u16* Wkl, u16* Wvh, u16* Woh) {
  size_t i = (size_t)blockIdx.x * 256 + threadIdx.x;
  const size_t NX = 8388608, NW = 4194304;
  if (i < NX) {
    float v = x[i];
    u16 h = f2h(v);
    xh[i] = h; xl[i] = f2h(v - h2f(h));
  } else {
    size_t j = i - NX;
    int wsel = (int)(j >> 22);
    size_t o = j & (NW - 1);
    if (wsel == 0) { float v = Wq[o] * 64.f; u16 h = f2h(v); Wqh[o] = h; Wql[o] = f2h(v - h2f(h)); }
    else if (wsel == 1) { float v = Wk[o] * 64.f; u16 h = f2h(v); Wkh[o] = h; Wkl[o] = f2h(v - h2f(h)); }
    else if (wsel == 2) { Wvh[o] = f2h(Wv[o] * 64.f); }
    else { Woh[o] = f2h(Wo[o] * 64.f); }
  }
}

// XCD-aware bijective remap for the 16x32 GEMM grid (512 blocks, out_kernel):
// HW XCD ~ dispatch_id % 8. XCD k owns an 8x8 rectangle of (by,bx) tiles.
__device__ __forceinline__ void xcd_map_gemm(int& m0, int& n0) {
  const int lin = blockIdx.x | (blockIdx.y << 4);
  const int k = lin & 7, j = lin >> 3;          // k = XCD, j = 0..63
  const int by = ((k >> 1) << 3) | (j >> 3);
  const int bx = ((k & 1) << 3) | (j & 7);
  m0 = by << 7; n0 = bx << 7;
}

// qkv remap (1536 blocks): z INTERLEAVED so each XCD's dispatch sequence
// cycles Q->K->V (heavy NT3 blocks co-resident with light NT1 blocks ->
// cross-block MFMA/VALU overlap, no all-V tail), while all three z of a
// given (by,bx) tile land on the SAME XCD (shared xh/xl panels in one L2).
__device__ __forceinline__ void xcd_map_qkv(int& z, int& m0, int& n0) {
  const int lin = blockIdx.x | (blockIdx.y << 4) | (blockIdx.z << 9);  // 0..1535
  const int k = lin & 7, j = lin >> 3;          // k = XCD, j = 0..191
  z = j % 3;
  const int jj = j / 3;                          // 0..63
  const int by = ((k >> 1) << 3) | (jj >> 3);
  const int bx = ((k & 1) << 3) | (jj & 7);
  m0 = by << 7; n0 = bx << 7;
}

// ---------------------------------------------------------------------------
// C[M,N] = A * B^T, fp16 MFMA, 128x128 tile, 256 thr = 4 waves (2M x 2N),
// BK=32. Round-3 verified staging (coalesced 16x64B rows + coalescing-neutral
// XOR chunk swizzle; bit-identical data) + round-5 counted-vmcnt schedule
// (known 251 us):
//
//   NT==3: double-buffered (2 x 16K u16). Per K-step, 2 phases:
//     ph1: WAITVM(4) [h(t) landed]  SBAR  ds_read ah,bh  stage h(t+1)
//          16 MFMA (ah*bh)
//     ph2: WAITVM(4) [l(t) landed]  SBAR  ds_read bl,al  stage l(t+1)
//          32 MFMA (ah*bl, al*bh)
//     vmcnt oscillates 8 -> 4: never drained to 0 in the main loop.
//   NT==1: triple-buffered (3 x 8K u16), depth-2 prefetch, WAITVM(4)/step.
//
// Round-7: staging addresses hoisted -- loop-invariant 32-bit lane offsets
// (offA0..offB1) + uniform (base + k0) pointer per stage call, so per-step
// address cost is SALU base arithmetic (saddr-form global_load_lds), cutting
// K-loop VALU.
//
// NT==3: AhBh+AhBl+AlBh   NT==1: AhBh
// MODE 0: f32*oscale -> Cf
// MODE 2: V^T fp16 -> Ch  ([b][h][d][s])
// MODE 3: fused RoPE -> fp16 single Ch (tile = one full head; d<->d+64
//         exchanged through LDS per i-block; oscale folds the q prescale).
// ---------------------------------------------------------------------------
template <int NT, int MODE>
__device__ __forceinline__ void gemm_core(
    u16* sm, const u16* __restrict__ Am, const u16* __restrict__ Alm,
    const u16* __restrict__ Bm, const u16* __restrict__ Blm,
    float* __restrict__ Cf, u16* __restrict__ Ch,
    const float* __restrict__ cosT, const float* __restrict__ sinT,
    int N, int K, int m0, int n0, float oscale) {
  const int tid = threadIdx.x;
  const int w = tid >> 6, lane = tid & 63;
  const int quad = lane >> 4, l16 = lane & 15;
  const int wm = (w >> 1) << 6, wn = (w & 1) << 6;
  const int lrow = lane >> 2, lcol = (lane & 3) << 3;
  // source-side swizzle (u16 units): chunk ^= (row>>1)&3  (coalescing-neutral)
  const int lcs = lcol ^ (((lrow >> 1) & 3) << 3);
  // read-side swizzle: same involution
  const int qsw = (quad << 3) ^ (((l16 >> 1) & 3) << 3);

  // loop-invariant per-lane offsets (u16 units, 32-bit) + LDS dest bases
  const int r0 = w * 32 + lrow;
  const int offA0 = (m0 + r0) * K + lcs;
  const int offA1 = offA0 + (K << 4);     // +16 rows
  const int offB0 = (n0 + r0) * K + lcs;
  const int offB1 = offB0 + (K << 4);
  const int ld0 = (w * 32) * 32;          // LDS dest (u16), j=0
  const int ld1 = (w * 32 + 16) * 32;     // j=1

  // stage h-parts (Ah,Bh) of K-tile at col k0 into buffer base bufb
  auto stageH = [&](int bufb, int k0) {
    const u16* A_k = Am + k0;
    const u16* B_k = Bm + k0;
    gload16(A_k + offA0, &sm[bufb + ld0]);
    gload16(A_k + offA1, &sm[bufb + ld1]);
    gload16(B_k + offB0, &sm[bufb + 4096 + ld0]);
    gload16(B_k + offB1, &sm[bufb + 4096 + ld1]);
  };
  // stage l-parts (Bl,Al)
  auto stageL = [&](int bufb, int k0) {
    const u16* Bl_k = Blm + k0;
    const u16* Al_k = Alm + k0;
    gload16(Bl_k + offB0, &sm[bufb + 8192 + ld0]);
    gload16(Bl_k + offB1, &sm[bufb + 8192 + ld1]);
    gload16(Al_k + offA0, &sm[bufb + 12288 + ld0]);
    gload16(Al_k + offA1, &sm[bufb + 12288 + ld1]);
  };

  f32x4 acc[4][4];
#pragma unroll
  for (int i = 0; i < 4; ++i)
#pragma unroll
    for (int n = 0; n < 4; ++n) acc[i][n] = (f32x4){0.f, 0.f, 0.f, 0.f};

  const int NTL = K >> 5;

  if (NT == 3) {
    stageH(0, 0);   // 4 loads
    stageL(0, 0);   // 4 loads -> 8 outstanding
    for (int t = 0; t < NTL; ++t) {
      const int cur = (t & 1) << 14;      // 0 / 16384
      const int nxt = 16384 - cur;
      const int k0n = (t + 1) << 5;
      const bool more = (t + 1 < NTL);

      // ---- phase 1: Ah x Bh ----
      WAITVM(4);    // h(t) landed (l(t) stays in flight)
      SBAR();
      f16x8 ah[4], bh[4];
#pragma unroll
      for (int i = 0; i < 4; ++i)
        ah[i] = *(const f16x8*)&sm[cur + (wm + i * 16 + l16) * 32 + qsw];
#pragma unroll
      for (int n = 0; n < 4; ++n)
        bh[n] = *(const f16x8*)&sm[cur + 4096 + (wn + n * 16 + l16) * 32 + qsw];
      if (more) stageH(nxt, k0n);
#pragma unroll
      for (int i = 0; i < 4; ++i)
#pragma unroll
        for (int n = 0; n < 4; ++n)
          acc[i][n] = __builtin_amdgcn_mfma_f32_16x16x32_f16(ah[i], bh[n], acc[i][n], 0, 0, 0);

      // ---- phase 2: Ah x Bl + Al x Bh ----
      if (more) { WAITVM(4); } else { WAITVM(0); }  // l(t) landed
      SBAR();
      f16x8 bl[4], al[4];
#pragma unroll
      for (int n = 0; n < 4; ++n)
        bl[n] = *(const f16x8*)&sm[cur + 8192 + (wn + n * 16 + l16) * 32 + qsw];
#pragma unroll
      for (int i = 0; i < 4; ++i)
        al[i] = *(const f16x8*)&sm[cur + 12288 + (wm + i * 16 + l16) * 32 + qsw];
      if (more) stageL(nxt, k0n);
#pragma unroll
      for (int i = 0; i < 4; ++i)
#pragma unroll
        for (int n = 0; n < 4; ++n) {
          acc[i][n] = __builtin_amdgcn_mfma_f32_16x16x32_f16(ah[i], bl[n], acc[i][n], 0, 0, 0);
          acc[i][n] = __builtin_amdgcn_mfma_f32_16x16x32_f16(al[i], bh[n], acc[i][n], 0, 0, 0);
        }
    }
  } else {
    stageH(0, 0);       // tile 0
    stageH(8192, 32);   // tile 1 -> 8 outstanding
    for (int t = 0; t < NTL; ++t) {
      const int cur = (t % 3) * 8192;
      if (t + 1 < NTL) { WAITVM(4); } else { WAITVM(0); }  // tile t landed
      SBAR();
      f16x8 ah[4], bh[4];
#pragma unroll
      for (int i = 0; i < 4; ++i)
        ah[i] = *(const f16x8*)&sm[cur + (wm + i * 16 + l16) * 32 + qsw];
#pragma unroll
      for (int n = 0; n < 4; ++n)
        bh[n] = *(const f16x8*)&sm[cur + 4096 + (wn + n * 16 + l16) * 32 + qsw];
      if (t + 2 < NTL) stageH(((t + 2) % 3) * 8192, (t + 2) << 5);
#pragma unroll
      for (int i = 0; i < 4; ++i)
#pragma unroll
        for (int n = 0; n < 4; ++n)
          acc[i][n] = __builtin_amdgcn_mfma_f32_16x16x32_f16(ah[i], bh[n], acc[i][n], 0, 0, 0);
    }
  }

  // epilogue: C/D layout row=(lane>>4)*4+r, col=lane&15
  if (MODE == 3) {
    // fused RoPE: tile cols n0..n0+127 are exactly one head (d = local col).
    float* fs = (float*)sm;  // 2 pairs x 16 rows x 128 cols f32 = 16 KiB
    const int p = w >> 1;
#pragma unroll
    for (int i = 0; i < 4; ++i) {
      __syncthreads();  // prev i-block reads (or K-loop LDS reads) done
#pragma unroll
      for (int n = 0; n < 4; ++n)
#pragma unroll
        for (int r = 0; r < 4; ++r)
          fs[p * 2048 + (quad * 4 + r) * 128 + wn + n * 16 + l16] = acc[i][n][r];
      __syncthreads();
#pragma unroll
      for (int n = 0; n < 4; ++n) {
        const int col = wn + n * 16 + l16;
        const int cc = col ^ 64;
        const float sgn = (col < 64) ? -1.f : 1.f;
#pragma unroll
        for (int r = 0; r < 4; ++r) {
          const int row16 = quad * 4 + r;
          const int grow = m0 + wm + i * 16 + row16;
          const int s = grow & (S_CTX - 1);
          const float c = cosT[s * 128 + col];
          const float sn = sinT[s * 128 + col];
          const float x = fs[p * 2048 + row16 * 128 + col];
          const float xp = fs[p * 2048 + row16 * 128 + cc];
          Ch[(size_t)grow * N + n0 + col] = f2h((x * c + sgn * xp * sn) * oscale);
        }
      }
    }
    return;
  }
#pragma unroll
  for (int i = 0; i < 4; ++i)
#pragma unroll
    for (int n = 0; n < 4; ++n) {
      const int row0 = m0 + wm + i * 16 + quad * 4;
      const int col = n0 + wn + n * 16 + l16;
      if (MODE == 0) {
#pragma unroll
        for (int r = 0; r < 4; ++r) Cf[(size_t)(row0 + r) * N + col] = acc[i][n][r] * oscale;
      } else {
        int brow = row0 >> 11, s0 = row0 & 2047;
        int hh = col >> 7, d = col & 127;
        ushort4 pk;
        pk.x = f2h(acc[i][n][0]);
        pk.y = f2h(acc[i][n][1]);
        pk.z = f2h(acc[i][n][2]);
        pk.w = f2h(acc[i][n][3]);
        *(ushort4*)(Ch + ((size_t)(brow * 16 + hh) * 128 + d) * 2048 + s0) = pk;
      }
    }
}

// Fused QKV projection + RoPE: grid (16, 32, 3), z-interleaved XCD remap.
// z=0: Q (3-term, rope + qs prescale); z=1: K (3-term, rope); z=2: V (1-term, V^T out)
__global__ __launch_bounds__(256) void qkv_kernel(
    const u16* __restrict__ xh, const u16* __restrict__ xl,
    const u16* __restrict__ Wqh, const u16* __restrict__ Wql,
    const u16* __restrict__ Wkh, const u16* __restrict__ Wkl,
    const u16* __restrict__ Wvh,
    const float* __restrict__ cosT, const float* __restrict__ sinT,
    u16* qh, u16* kh, u16* vt) {
  __shared__ u16 sm[32768];  // 64 KiB: 2 x 16K u16 (NT3 dbuf) / 3 x 8K (NT1)
  int z, m0, n0;
  xcd_map_qkv(z, m0, n0);
  const float qs = 0.002762135864009951f;  // sqrt(128)/4096
  if (z == 0)
    gemm_core<3, 3>(sm, xh, xl, Wqh, Wql, nullptr, qh, cosT, sinT, DMODEL, DMODEL, m0, n0, qs);
  else if (z == 1)
    gemm_core<3, 3>(sm, xh, xl, Wkh, Wkl, nullptr, kh, cosT, sinT, DMODEL, DMODEL, m0, n0, 1.f);
  else
    gemm_core<1, 2>(sm, xh, nullptr, Wvh, nullptr, nullptr, vt, nullptr, nullptr, DMODEL, DMODEL, m0, n0, 1.f);
}

// out = (ch * Woh^T) / 4096  (1-term fp16; dropped terms ~1.5e-4)
__global__ __launch_bounds__(256) void out_kernel(
    const u16* __restrict__ ch, const u16* __restrict__ Woh, float* __restrict__ out) {
  __shared__ u16 sm[24576];  // 48 KiB: 3 x 8K u16
  int m0, n0;
  xcd_map_gemm(m0, n0);
  gemm_core<1, 0>(sm, ch, nullptr, Woh, nullptr, out, nullptr, nullptr, nullptr, DMODEL, DMODEL,
                  m0, n0, 1.f / 4096.f);
}

// Flash attention, causal. 1-term fp16 QK (q pre-scaled), f32 online softmax,
// fp16 P and PV with V^T [b][h][d][s]. BQ=128: 512 thr = 8 waves x 16 q-rows
// sharing K/V tiles (BK=64). P in its OWN per-wave LDS buffer. 2 barriers/iter.
// Register prefetch of tile kt+1.
//
// CAUSAL LOAD BALANCE (round 5): block bx does q-tiles {15-bx, bx}: 34
// k-tile-steps for EVERY block; 256 blocks = 1/CU, no tail.
// XCD REMAP (round 6): XCD k owns all 8 q-blocks of bh in [4k, 4k+4).
// Round 7: s_setprio(1) around QK^T and PV MFMA clusters (T5; attn blocks
// are independent -> scheduler can favor MFMA-entering waves, m191 +4-7%).
__global__ __launch_bounds__(512) void attn_kernel(
    const u16* __restrict__ Qh, const u16* __restrict__ Kh,
    const u16* __restrict__ VT, u16* __restrict__ Ch) {
  const int lin = blockIdx.x | (blockIdx.y << 3);  // 0..255
  const int xk = lin & 7, lj = lin >> 3;           // xk = XCD, lj = 0..31
  const int bh = (xk << 2) | (lj >> 3);            // 4 bh per XCD
  const int bx = lj & 7;                           // q-pair index 0..7
  const int b = bh >> 4, h = bh & 15;
  const int tid = threadIdx.x;
  const int w = tid >> 6, lane = tid & 63;
  const int quad = lane >> 4, l16 = lane & 15;

  __shared__ u16 sKh[64 * 136];   // K-tile [k][d] pitch 136
  __shared__ u16 sVt[128 * 72];   // V^T tile [d][k], pitch 72
  __shared__ u16 sPb[8 * 1088];   // per-wave P, 16 x 68 each (dedicated)
  u16* sP = &sPb[w * 1088];

  const size_t bhbase = (size_t)b * S_CTX * DMODEL + (size_t)h * 128;
  const size_t vtbase = (size_t)bh * 128 * 2048;

  int kr[2], kc[2], vr[2], vc[2];
#pragma unroll
  for (int j = 0; j < 2; ++j) {
    int c = j * 512 + tid;
    kr[j] = c >> 4; kc[j] = (c & 15) << 3;
    vr[j] = c >> 3; vc[j] = (c & 7) << 3;
  }

#pragma unroll 1
  for (int pass = 0; pass < 2; ++pass) {
    const int qt = pass ? bx : 15 - bx;  // heavy q-tile first

    // Q fragments; wave w owns q-rows qt*128 + w*16 + [0,16)
    const int qr0 = qt * 128 + w * 16;
    const size_t qoff = bhbase + (size_t)(qr0 + l16) * DMODEL;
    f16x8 qf[4];
#pragma unroll
    for (int c = 0; c < 4; ++c) qf[c] = *(const f16x8*)(Qh + qoff + c * 32 + quad * 8);

    f32x4 oacc[8];
#pragma unroll
    for (int d = 0; d < 8; ++d) oacc[d] = (f32x4){0.f, 0.f, 0.f, 0.f};
    float m_r[4] = {-INFINITY, -INFINITY, -INFINITY, -INFINITY};
    float l_r[4] = {0.f, 0.f, 0.f, 0.f};

    f16x8 rkh[2], rvt[2];
#pragma unroll
    for (int j = 0; j < 2; ++j) {
      rkh[j] = *(const f16x8*)(Kh + bhbase + (size_t)kr[j] * DMODEL + kc[j]);
      rvt[j] = *(const f16x8*)(VT + vtbase + (size_t)vr[j] * 2048 + vc[j]);
    }

    const int nkt = 2 * qt + 2;
    for (int kt = 0; kt < nkt; ++kt) {
      __syncthreads();  // (1) prev iter (or prev pass) LDS reads done
#pragma unroll
      for (int j = 0; j < 2; ++j) {
        *(f16x8*)&sKh[kr[j] * 136 + kc[j]] = rkh[j];
        *(f16x8*)&sVt[vr[j] * 72 + vc[j]] = rvt[j];
      }
      __syncthreads();  // (2) tiles visible
      if (kt + 1 < nkt) {
#pragma unroll
        for (int j = 0; j < 2; ++j) {
          size_t g = bhbase + (size_t)((kt + 1) * 64 + kr[j]) * DMODEL + kc[j];
          rkh[j] = *(const f16x8*)(Kh + g);
          rvt[j] = *(const f16x8*)(VT + vtbase + (size_t)vr[j] * 2048 + (kt + 1) * 64 + vc[j]);
        }
      }

      const bool active = (kt * 64) <= (qr0 + 15);
      if (active) {
        f32x4 sacc[4];
#pragma unroll
        for (int n = 0; n < 4; ++n) sacc[n] = (f32x4){0.f, 0.f, 0.f, 0.f};
        __builtin_amdgcn_s_setprio(1);
#pragma unroll
        for (int n = 0; n < 4; ++n)
#pragma unroll
          for (int c = 0; c < 4; ++c) {
            f16x8 kf = *(const f16x8*)&sKh[(n * 16 + l16) * 136 + c * 32 + quad * 8];
            sacc[n] = __builtin_amdgcn_mfma_f32_16x16x32_f16(qf[c], kf, sacc[n], 0, 0, 0);
          }
        __builtin_amdgcn_s_setprio(0);

        float pm[4][4];
        float rowmax[4] = {-INFINITY, -INFINITY, -INFINITY, -INFINITY};
#pragma unroll
        for (int n = 0; n < 4; ++n)
#pragma unroll
          for (int r = 0; r < 4; ++r) {
            float sc = sacc[n][r];
            int qi = qr0 + quad * 4 + r;
            int ki = kt * 64 + n * 16 + l16;
            if (ki > qi) sc = -INFINITY;
            pm[n][r] = sc;
            rowmax[r] = fmaxf(rowmax[r], sc);
          }
#pragma unroll
        for (int off = 1; off < 16; off <<= 1)
#pragma unroll
          for (int r = 0; r < 4; ++r)
            rowmax[r] = fmaxf(rowmax[r], __shfl_xor(rowmax[r], off, 64));

        float alphav[4];
#pragma unroll
        for (int r = 0; r < 4; ++r) {
          float mnew = fmaxf(m_r[r], rowmax[r]);
          alphav[r] = __expf(m_r[r] - mnew);
          m_r[r] = mnew;
          l_r[r] *= alphav[r];
        }
        float rowsum[4] = {0.f, 0.f, 0.f, 0.f};
#pragma unroll
        for (int n = 0; n < 4; ++n)
#pragma unroll
          for (int r = 0; r < 4; ++r) {
            float p = __expf(pm[n][r] - m_r[r]);
            pm[n][r] = p;
            rowsum[r] += p;
          }
#pragma unroll
        for (int off = 1; off < 16; off <<= 1)
#pragma unroll
          for (int r = 0; r < 4; ++r) rowsum[r] += __shfl_xor(rowsum[r], off, 64);
#pragma unroll
        for (int r = 0; r < 4; ++r) l_r[r] += rowsum[r];

#pragma unroll
        for (int d = 0; d < 8; ++d)
#pragma unroll
          for (int r = 0; r < 4; ++r) oacc[d][r] *= alphav[r];

        // P (C-layout) -> per-wave dedicated LDS region -> A-layout
#pragma unroll
        for (int n = 0; n < 4; ++n)
#pragma unroll
          for (int r = 0; r < 4; ++r)
            sP[(quad * 4 + r) * 68 + n * 16 + l16] = f2h(pm[n][r]);

        // O += P.V
        __builtin_amdgcn_s_setprio(1);
#pragma unroll
        for (int c = 0; c < 2; ++c) {
          f16x8 pf = *(const f16x8*)&sP[l16 * 68 + c * 32 + quad * 8];
#pragma unroll
          for (int d = 0; d < 8; ++d) {
            f16x8 vf = *(const f16x8*)&sVt[(d * 16 + l16) * 72 + c * 32 + quad * 8];
            oacc[d] = __builtin_amdgcn_mfma_f32_16x16x32_f16(pf, vf, oacc[d], 0, 0, 0);
          }
        }
        __builtin_amdgcn_s_setprio(0);
      }
    }

    float invl[4];
#pragma unroll
    for (int r = 0; r < 4; ++r) invl[r] = 1.f / l_r[r];
#pragma unroll
    for (int d = 0; d < 8; ++d)
#pragma unroll
      for (int r = 0; r < 4; ++r) {
        int row = qr0 + quad * 4 + r;
        Ch[bhbase + (size_t)row * DMODEL + d * 16 + l16] = f2h(oacc[d][r] * invl[r]);
      }
  }
}

extern "C" void kernel_launch(void* const* d_in, const int* in_sizes, int n_in,
                              void* d_out, int out_size, void* d_ws, size_t ws_size,
                              hipStream_t stream) {
  const float* x    = (const float*)d_in[0];
  const float* Wq   = (const float*)d_in[1];
  const float* Wk   = (const float*)d_in[2];
  const float* Wv   = (const float*)d_in[3];
  const float* Wo   = (const float*)d_in[4];
  const float* cosT = (const float*)d_in[5];
  const float* sinT = (const float*)d_in[6];
  float* out = (float*)d_out;

  const size_t NX = 8388608;   // 2*2048*2048
  const size_t NW = 4194304;   // 2048*2048
  u16* p = (u16*)d_ws;
  u16* xh  = p; p += NX;  u16* xl  = p; p += NX;
  u16* Wqh = p; p += NW;  u16* Wql = p; p += NW;
  u16* Wkh = p; p += NW;  u16* Wkl = p; p += NW;
  u16* Wvh = p; p += NW;  u16* Woh = p; p += NW;
  u16* qh  = p; p += NX;  u16* kh  = p; p += NX;
  u16* vt  = p; p += NX;
  u16* ch  = p; p += NX;
  // ~150 MiB of d_ws

  split_all<<<98304, 256, 0, stream>>>(x, Wq, Wk, Wv, Wo,
                                       xh, xl, Wqh, Wql, Wkh, Wkl, Wvh, Woh);

  qkv_kernel<<<dim3(16, 32, 3), 256, 0, stream>>>(xh, xl, Wqh, Wql, Wkh, Wkl, Wvh,
                                                  cosT, sinT, qh, kh, vt);

  attn_kernel<<<dim3(8, 32), 512, 0, stream>>>(qh, kh, vt, ch);

  out_kernel<<<dim3(16, 32), 256, 0, stream>>>(ch, Woh, out);
}

// Round 8
// 548.193 us; speedup vs baseline: 1.0894x; 1.0894x over previous
//
#include <hip/hip_runtime.h>

typedef unsigned short u16;
typedef __attribute__((ext_vector_type(8))) _Float16 f16x8;
typedef __attribute__((ext_vector_type(4))) float f32x4;

#define S_CTX 2048
#define DMODEL 2048

#define WAITVM(N) asm volatile("s_waitcnt vmcnt(" #N ")" ::: "memory")
#define SBAR() __builtin_amdgcn_s_barrier()

__device__ __forceinline__ u16 f2h(float f) {
  _Float16 h = (_Float16)f; u16 u; __builtin_memcpy(&u, &h, 2); return u;
}
__device__ __forceinline__ float h2f(u16 u) {
  _Float16 h; __builtin_memcpy(&h, &u, 2); return (float)h;
}
__device__ __forceinline__ void gload16(const u16* g, u16* l) {
  __builtin_amdgcn_global_load_lds(
      (const __attribute__((address_space(1))) unsigned int*)g,
      (__attribute__((address_space(3))) unsigned int*)l, 16, 0, 0);
}

// One fused split pass. x -> fp16 pair (no scale). Wq,Wk -> fp16 pair (x64).
// Wv,Wo -> fp16 single (x64). Scales folded out downstream (q-prescale, /4096).
__global__ void split_all(const float* __restrict__ x, const float* __restrict__ Wq,
                          const float* __restrict__ Wk, const float* __restrict__ Wv,
                          const float* __restrict__ Wo,
                          u16* xh, u16* xl, u16* Wqh, u16* Wql,
                          u16* Wkh, u16* Wkl, u16* Wvh, u16* Woh) {
  size_t i = (size_t)blockIdx.x * 256 + threadIdx.x;
  const size_t NX = 8388608, NW = 4194304;
  if (i < NX) {
    float v = x[i];
    u16 h = f2h(v);
    xh[i] = h; xl[i] = f2h(v - h2f(h));
  } else {
    size_t j = i - NX;
    int wsel = (int)(j >> 22);
    size_t o = j & (NW - 1);
    if (wsel == 0) { float v = Wq[o] * 64.f; u16 h = f2h(v); Wqh[o] = h; Wql[o] = f2h(v - h2f(h)); }
    else if (wsel == 1) { float v = Wk[o] * 64.f; u16 h = f2h(v); Wkh[o] = h; Wkl[o] = f2h(v - h2f(h)); }
    else if (wsel == 2) { Wvh[o] = f2h(Wv[o] * 64.f); }
    else { Woh[o] = f2h(Wo[o] * 64.f); }
  }
}

// ---------------------------------------------------------------------------
// C[M,N] = A * B^T, fp16 MFMA, 128x128 tile, 256 thr = 4 waves (2M x 2N),
// BK=32. Round-5 EXACT core (best measured: qkv 251 us): coalesced 16x64B-row
// staging + coalescing-neutral XOR chunk swizzle + counted-vmcnt pipeline.
// Identity block mapping (r6/r7 showed XCD remaps don't beat it in time).
//
//   NT==3: double-buffered (2 x 16K u16). Per K-step, 2 phases:
//     ph1: WAITVM(4) [h(t) landed]  SBAR  ds_read ah,bh  stage h(t+1)
//          16 MFMA (ah*bh)
//     ph2: WAITVM(4) [l(t) landed]  SBAR  ds_read bl,al  stage l(t+1)
//          32 MFMA (ah*bl, al*bh)
//     vmcnt oscillates 8 -> 4: never drained to 0 in the main loop.
//   NT==1: triple-buffered (3 x 8K u16), depth-2 prefetch, WAITVM(4)/step.
//
// NT==3: AhBh+AhBl+AlBh   NT==1: AhBh
// MODE 0: f32*oscale -> Cf
// MODE 2: V^T fp16 -> Ch  ([b][h][d][s])
// MODE 3: fused RoPE -> fp16 single Ch (tile = one full head; d<->d+64
//         exchanged through LDS per i-block; oscale folds the q prescale).
// ---------------------------------------------------------------------------
template <int NT, int MODE>
__device__ __forceinline__ void gemm_core(
    u16* sm, const u16* __restrict__ Am, const u16* __restrict__ Alm,
    const u16* __restrict__ Bm, const u16* __restrict__ Blm,
    float* __restrict__ Cf, u16* __restrict__ Ch,
    const float* __restrict__ cosT, const float* __restrict__ sinT,
    int N, int K, int m0, int n0, float oscale) {
  const int tid = threadIdx.x;
  const int w = tid >> 6, lane = tid & 63;
  const int quad = lane >> 4, l16 = lane & 15;
  const int wm = (w >> 1) << 6, wn = (w & 1) << 6;
  const int lrow = lane >> 2, lcol = (lane & 3) << 3;
  // source-side swizzle (u16 units): chunk ^= (row>>1)&3  (coalescing-neutral)
  const int lcs = lcol ^ (((lrow >> 1) & 3) << 3);
  // read-side swizzle: same involution
  const int qsw = (quad << 3) ^ (((l16 >> 1) & 3) << 3);

  // stage h-parts (Ah,Bh) of one K-tile into buffer at base bufb (u16 units)
  auto stageH = [&](int bufb, int k0) {
#pragma unroll
    for (int j = 0; j < 2; ++j) {
      int r = w * 32 + j * 16 + lrow;
      int lb = bufb + (w * 32 + j * 16) * 32;
      size_t ga = (size_t)(m0 + r) * K + k0 + lcs;
      size_t gb = (size_t)(n0 + r) * K + k0 + lcs;
      gload16(Am + ga, &sm[lb]);
      gload16(Bm + gb, &sm[lb + 4096]);
    }
  };
  // stage l-parts (Bl,Al)
  auto stageL = [&](int bufb, int k0) {
#pragma unroll
    for (int j = 0; j < 2; ++j) {
      int r = w * 32 + j * 16 + lrow;
      int lb = bufb + (w * 32 + j * 16) * 32;
      size_t ga = (size_t)(m0 + r) * K + k0 + lcs;
      size_t gb = (size_t)(n0 + r) * K + k0 + lcs;
      gload16(Blm + gb, &sm[lb + 8192]);
      gload16(Alm + ga, &sm[lb + 12288]);
    }
  };

  f32x4 acc[4][4];
#pragma unroll
  for (int i = 0; i < 4; ++i)
#pragma unroll
    for (int n = 0; n < 4; ++n) acc[i][n] = (f32x4){0.f, 0.f, 0.f, 0.f};

  const int NTL = K >> 5;

  if (NT == 3) {
    stageH(0, 0);   // 4 loads
    stageL(0, 0);   // 4 loads -> 8 outstanding
    for (int t = 0; t < NTL; ++t) {
      const int cur = (t & 1) << 14;      // 0 / 16384
      const int nxt = 16384 - cur;
      const int k0n = (t + 1) << 5;
      const bool more = (t + 1 < NTL);

      // ---- phase 1: Ah x Bh ----
      WAITVM(4);    // h(t) landed (l(t) stays in flight)
      SBAR();
      f16x8 ah[4], bh[4];
#pragma unroll
      for (int i = 0; i < 4; ++i)
        ah[i] = *(const f16x8*)&sm[cur + (wm + i * 16 + l16) * 32 + qsw];
#pragma unroll
      for (int n = 0; n < 4; ++n)
        bh[n] = *(const f16x8*)&sm[cur + 4096 + (wn + n * 16 + l16) * 32 + qsw];
      if (more) stageH(nxt, k0n);
#pragma unroll
      for (int i = 0; i < 4; ++i)
#pragma unroll
        for (int n = 0; n < 4; ++n)
          acc[i][n] = __builtin_amdgcn_mfma_f32_16x16x32_f16(ah[i], bh[n], acc[i][n], 0, 0, 0);

      // ---- phase 2: Ah x Bl + Al x Bh ----
      if (more) { WAITVM(4); } else { WAITVM(0); }  // l(t) landed
      SBAR();
      f16x8 bl[4], al[4];
#pragma unroll
      for (int n = 0; n < 4; ++n)
        bl[n] = *(const f16x8*)&sm[cur + 8192 + (wn + n * 16 + l16) * 32 + qsw];
#pragma unroll
      for (int i = 0; i < 4; ++i)
        al[i] = *(const f16x8*)&sm[cur + 12288 + (wm + i * 16 + l16) * 32 + qsw];
      if (more) stageL(nxt, k0n);
#pragma unroll
      for (int i = 0; i < 4; ++i)
#pragma unroll
        for (int n = 0; n < 4; ++n) {
          acc[i][n] = __builtin_amdgcn_mfma_f32_16x16x32_f16(ah[i], bl[n], acc[i][n], 0, 0, 0);
          acc[i][n] = __builtin_amdgcn_mfma_f32_16x16x32_f16(al[i], bh[n], acc[i][n], 0, 0, 0);
        }
    }
  } else {
    stageH(0, 0);       // tile 0
    stageH(8192, 32);   // tile 1 -> 8 outstanding
    for (int t = 0; t < NTL; ++t) {
      const int cur = (t % 3) * 8192;
      if (t + 1 < NTL) { WAITVM(4); } else { WAITVM(0); }  // tile t landed
      SBAR();
      f16x8 ah[4], bh[4];
#pragma unroll
      for (int i = 0; i < 4; ++i)
        ah[i] = *(const f16x8*)&sm[cur + (wm + i * 16 + l16) * 32 + qsw];
#pragma unroll
      for (int n = 0; n < 4; ++n)
        bh[n] = *(const f16x8*)&sm[cur + 4096 + (wn + n * 16 + l16) * 32 + qsw];
      if (t + 2 < NTL) stageH(((t + 2) % 3) * 8192, (t + 2) << 5);
#pragma unroll
      for (int i = 0; i < 4; ++i)
#pragma unroll
        for (int n = 0; n < 4; ++n)
          acc[i][n] = __builtin_amdgcn_mfma_f32_16x16x32_f16(ah[i], bh[n], acc[i][n], 0, 0, 0);
    }
  }

  // epilogue: C/D layout row=(lane>>4)*4+r, col=lane&15
  if (MODE == 3) {
    // fused RoPE: tile cols n0..n0+127 are exactly one head (d = local col).
    float* fs = (float*)sm;  // 2 pairs x 16 rows x 128 cols f32 = 16 KiB
    const int p = w >> 1;
#pragma unroll
    for (int i = 0; i < 4; ++i) {
      __syncthreads();  // prev i-block reads (or K-loop LDS reads) done
#pragma unroll
      for (int n = 0; n < 4; ++n)
#pragma unroll
        for (int r = 0; r < 4; ++r)
          fs[p * 2048 + (quad * 4 + r) * 128 + wn + n * 16 + l16] = acc[i][n][r];
      __syncthreads();
#pragma unroll
      for (int n = 0; n < 4; ++n) {
        const int col = wn + n * 16 + l16;
        const int cc = col ^ 64;
        const float sgn = (col < 64) ? -1.f : 1.f;
#pragma unroll
        for (int r = 0; r < 4; ++r) {
          const int row16 = quad * 4 + r;
          const int grow = m0 + wm + i * 16 + row16;
          const int s = grow & (S_CTX - 1);
          const float c = cosT[s * 128 + col];
          const float sn = sinT[s * 128 + col];
          const float x = fs[p * 2048 + row16 * 128 + col];
          const float xp = fs[p * 2048 + row16 * 128 + cc];
          Ch[(size_t)grow * N + n0 + col] = f2h((x * c + sgn * xp * sn) * oscale);
        }
      }
    }
    return;
  }
#pragma unroll
  for (int i = 0; i < 4; ++i)
#pragma unroll
    for (int n = 0; n < 4; ++n) {
      const int row0 = m0 + wm + i * 16 + quad * 4;
      const int col = n0 + wn + n * 16 + l16;
      if (MODE == 0) {
#pragma unroll
        for (int r = 0; r < 4; ++r) Cf[(size_t)(row0 + r) * N + col] = acc[i][n][r] * oscale;
      } else {
        int brow = row0 >> 11, s0 = row0 & 2047;
        int hh = col >> 7, d = col & 127;
        ushort4 pk;
        pk.x = f2h(acc[i][n][0]);
        pk.y = f2h(acc[i][n][1]);
        pk.z = f2h(acc[i][n][2]);
        pk.w = f2h(acc[i][n][3]);
        *(ushort4*)(Ch + ((size_t)(brow * 16 + hh) * 128 + d) * 2048 + s0) = pk;
      }
    }
}

// Fused QKV projection + RoPE: grid (16, 32, 3).
// z=0: Q (3-term, rope + qs prescale); z=1: K (3-term, rope); z=2: V (1-term, V^T out)
__global__ __launch_bounds__(256) void qkv_kernel(
    const u16* __restrict__ xh, const u16* __restrict__ xl,
    const u16* __restrict__ Wqh, const u16* __restrict__ Wql,
    const u16* __restrict__ Wkh, const u16* __restrict__ Wkl,
    const u16* __restrict__ Wvh,
    const float* __restrict__ cosT, const float* __restrict__ sinT,
    u16* qh, u16* kh, u16* vt) {
  __shared__ u16 sm[32768];  // 64 KiB: 2 x 16K u16 (NT3 dbuf) / 3 x 8K (NT1)
  const int m0 = blockIdx.y << 7, n0 = blockIdx.x << 7;
  const float qs = 0.002762135864009951f;  // sqrt(128)/4096
  if (blockIdx.z == 0)
    gemm_core<3, 3>(sm, xh, xl, Wqh, Wql, nullptr, qh, cosT, sinT, DMODEL, DMODEL, m0, n0, qs);
  else if (blockIdx.z == 1)
    gemm_core<3, 3>(sm, xh, xl, Wkh, Wkl, nullptr, kh, cosT, sinT, DMODEL, DMODEL, m0, n0, 1.f);
  else
    gemm_core<1, 2>(sm, xh, nullptr, Wvh, nullptr, nullptr, vt, nullptr, nullptr, DMODEL, DMODEL, m0, n0, 1.f);
}

// out = (ch * Woh^T) / 4096  (1-term fp16; dropped terms ~1.5e-4)
__global__ __launch_bounds__(256) void out_kernel(
    const u16* __restrict__ ch, const u16* __restrict__ Woh, float* __restrict__ out) {
  __shared__ u16 sm[24576];  // 48 KiB: 3 x 8K u16
  gemm_core<1, 0>(sm, ch, nullptr, Woh, nullptr, out, nullptr, nullptr, nullptr, DMODEL, DMODEL,
                  blockIdx.y << 7, blockIdx.x << 7, 1.f / 4096.f);
}

// Flash attention, causal. 1-term fp16 QK (q pre-scaled), f32 online softmax,
// fp16 P and PV with V^T [b][h][d][s]. BQ=128: 512 thr = 8 waves x 16 q-rows
// sharing K/V tiles (BK=64). 2 barriers/iter; reg prefetch of tile kt+1.
// Causal pairing (r5): block bx does q-tiles {15-bx, bx}: 34 steps/block,
// 256 blocks = 1/CU, no tail.
//
// Round 8 — SWAPPED QK^T: sacc[n] = mfma(kf, qf) (same fragments, transposed
// output): thread (quad,l16) holds S[q = qr0+l16][k = kt*64+n*16+quad*4+r].
// Softmax reduction is now lane-local: 15 in-lane fmax/add + 2 shfl_xor
// (16,32) per max & sum (vs 32 shfl before); m/l/alpha are scalars; P packs
// to 4x ushort4 stores (r-contiguous k). PV needs 4 broadcast shfl to map
// alpha/invl to C-layout rows (quad*4+r). PV math unchanged.
__global__ __launch_bounds__(512) void attn_kernel(
    const u16* __restrict__ Qh, const u16* __restrict__ Kh,
    const u16* __restrict__ VT, u16* __restrict__ Ch) {
  const int bx = blockIdx.x;  // 0..7
  const int bh = blockIdx.y;
  const int b = bh >> 4, h = bh & 15;
  const int tid = threadIdx.x;
  const int w = tid >> 6, lane = tid & 63;
  const int quad = lane >> 4, l16 = lane & 15;

  __shared__ u16 sKh[64 * 136];   // K-tile [k][d] pitch 136
  __shared__ u16 sVt[128 * 72];   // V^T tile [d][k], pitch 72
  __shared__ u16 sPb[8 * 1088];   // per-wave P, 16 x 68 each (dedicated)
  u16* sP = &sPb[w * 1088];

  const size_t bhbase = (size_t)b * S_CTX * DMODEL + (size_t)h * 128;
  const size_t vtbase = (size_t)bh * 128 * 2048;

  int kr[2], kc[2], vr[2], vc[2];
#pragma unroll
  for (int j = 0; j < 2; ++j) {
    int c = j * 512 + tid;
    kr[j] = c >> 4; kc[j] = (c & 15) << 3;
    vr[j] = c >> 3; vc[j] = (c & 7) << 3;
  }

#pragma unroll 1
  for (int pass = 0; pass < 2; ++pass) {
    const int qt = pass ? bx : 15 - bx;  // heavy q-tile first

    // Q fragments; wave w owns q-rows qt*128 + w*16 + [0,16)
    const int qr0 = qt * 128 + w * 16;
    const size_t qoff = bhbase + (size_t)(qr0 + l16) * DMODEL;
    f16x8 qf[4];
#pragma unroll
    for (int c = 0; c < 4; ++c) qf[c] = *(const f16x8*)(Qh + qoff + c * 32 + quad * 8);

    f32x4 oacc[8];
#pragma unroll
    for (int d = 0; d < 8; ++d) oacc[d] = (f32x4){0.f, 0.f, 0.f, 0.f};
    float m_r = -INFINITY;  // running max for q-row qr0 + l16
    float l_r = 0.f;        // running denom for q-row qr0 + l16

    f16x8 rkh[2], rvt[2];
#pragma unroll
    for (int j = 0; j < 2; ++j) {
      rkh[j] = *(const f16x8*)(Kh + bhbase + (size_t)kr[j] * DMODEL + kc[j]);
      rvt[j] = *(const f16x8*)(VT + vtbase + (size_t)vr[j] * 2048 + vc[j]);
    }

    const int nkt = 2 * qt + 2;
    for (int kt = 0; kt < nkt; ++kt) {
      __syncthreads();  // (1) prev iter (or prev pass) LDS reads done
#pragma unroll
      for (int j = 0; j < 2; ++j) {
        *(f16x8*)&sKh[kr[j] * 136 + kc[j]] = rkh[j];
        *(f16x8*)&sVt[vr[j] * 72 + vc[j]] = rvt[j];
      }
      __syncthreads();  // (2) tiles visible
      if (kt + 1 < nkt) {
#pragma unroll
        for (int j = 0; j < 2; ++j) {
          size_t g = bhbase + (size_t)((kt + 1) * 64 + kr[j]) * DMODEL + kc[j];
          rkh[j] = *(const f16x8*)(Kh + g);
          rvt[j] = *(const f16x8*)(VT + vtbase + (size_t)vr[j] * 2048 + (kt + 1) * 64 + vc[j]);
        }
      }

      const bool active = (kt * 64) <= (qr0 + 15);
      if (active) {
        f32x4 sacc[4];
#pragma unroll
        for (int n = 0; n < 4; ++n) sacc[n] = (f32x4){0.f, 0.f, 0.f, 0.f};
        __builtin_amdgcn_s_setprio(1);
#pragma unroll
        for (int n = 0; n < 4; ++n)
#pragma unroll
          for (int c = 0; c < 4; ++c) {
            f16x8 kf = *(const f16x8*)&sKh[(n * 16 + l16) * 136 + c * 32 + quad * 8];
            sacc[n] = __builtin_amdgcn_mfma_f32_16x16x32_f16(kf, qf[c], sacc[n], 0, 0, 0);
          }
        __builtin_amdgcn_s_setprio(0);

        // thread's q-row: qi = qr0 + l16; score k = kt*64 + n*16 + quad*4 + r
        const int qi = qr0 + l16;
        const int kb = kt * 64 + quad * 4;
        float pm[4][4];
        float rmax = -INFINITY;
#pragma unroll
        for (int n = 0; n < 4; ++n)
#pragma unroll
          for (int r = 0; r < 4; ++r) {
            float sc = sacc[n][r];
            if (kb + n * 16 + r > qi) sc = -INFINITY;
            pm[n][r] = sc;
            rmax = fmaxf(rmax, sc);
          }
        rmax = fmaxf(rmax, __shfl_xor(rmax, 16, 64));
        rmax = fmaxf(rmax, __shfl_xor(rmax, 32, 64));

        const float mnew = fmaxf(m_r, rmax);
        const float alpha = __expf(m_r - mnew);
        m_r = mnew;
        l_r *= alpha;
        float rsum = 0.f;
#pragma unroll
        for (int n = 0; n < 4; ++n)
#pragma unroll
          for (int r = 0; r < 4; ++r) {
            float pv = __expf(pm[n][r] - m_r);
            pm[n][r] = pv;
            rsum += pv;
          }
        rsum += __shfl_xor(rsum, 16, 64);
        rsum += __shfl_xor(rsum, 32, 64);
        l_r += rsum;

        // redistribute alpha to PV C-layout rows (quad*4 + r)
        float apv[4];
#pragma unroll
        for (int r = 0; r < 4; ++r)
          apv[r] = __shfl(alpha, (lane & 48) | (quad * 4 + r), 64);
#pragma unroll
        for (int d = 0; d < 8; ++d)
#pragma unroll
          for (int r = 0; r < 4; ++r) oacc[d][r] *= apv[r];

        // P -> per-wave LDS (A-layout row = q-local l16), packed ushort4
#pragma unroll
        for (int n = 0; n < 4; ++n) {
          ushort4 pk;
          pk.x = f2h(pm[n][0]);
          pk.y = f2h(pm[n][1]);
          pk.z = f2h(pm[n][2]);
          pk.w = f2h(pm[n][3]);
          *(ushort4*)&sP[l16 * 68 + n * 16 + quad * 4] = pk;
        }

        // O += P.V
        __builtin_amdgcn_s_setprio(1);
#pragma unroll
        for (int c = 0; c < 2; ++c) {
          f16x8 pf = *(const f16x8*)&sP[l16 * 68 + c * 32 + quad * 8];
#pragma unroll
          for (int d = 0; d < 8; ++d) {
            f16x8 vf = *(const f16x8*)&sVt[(d * 16 + l16) * 72 + c * 32 + quad * 8];
            oacc[d] = __builtin_amdgcn_mfma_f32_16x16x32_f16(pf, vf, oacc[d], 0, 0, 0);
          }
        }
        __builtin_amdgcn_s_setprio(0);
      }
    }

    const float invl = 1.f / l_r;
    float ipv[4];
#pragma unroll
    for (int r = 0; r < 4; ++r)
      ipv[r] = __shfl(invl, (lane & 48) | (quad * 4 + r), 64);
#pragma unroll
    for (int d = 0; d < 8; ++d)
#pragma unroll
      for (int r = 0; r < 4; ++r) {
        int row = qr0 + quad * 4 + r;
        Ch[bhbase + (size_t)row * DMODEL + d * 16 + l16] = f2h(oacc[d][r] * ipv[r]);
      }
  }
}

extern "C" void kernel_launch(void* const* d_in, const int* in_sizes, int n_in,
                              void* d_out, int out_size, void* d_ws, size_t ws_size,
                              hipStream_t stream) {
  const float* x    = (const float*)d_in[0];
  const float* Wq   = (const float*)d_in[1];
  const float* Wk   = (const float*)d_in[2];
  const float* Wv   = (const float*)d_in[3];
  const float* Wo   = (const float*)d_in[4];
  const float* cosT = (const float*)d_in[5];
  const float* sinT = (const float*)d_in[6];
  float* out = (float*)d_out;

  const size_t NX = 8388608;   // 2*2048*2048
  const size_t NW = 4194304;   // 2048*2048
  u16* p = (u16*)d_ws;
  u16* xh  = p; p += NX;  u16* xl  = p; p += NX;
  u16* Wqh = p; p += NW;  u16* Wql = p; p += NW;
  u16* Wkh = p; p += NW;  u16* Wkl = p; p += NW;
  u16* Wvh = p; p += NW;  u16* Woh = p; p += NW;
  u16* qh  = p; p += NX;  u16* kh  = p; p += NX;
  u16* vt  = p; p += NX;
  u16* ch  = p; p += NX;
  // ~150 MiB of d_ws

  split_all<<<98304, 256, 0, stream>>>(x, Wq, Wk, Wv, Wo,
                                       xh, xl, Wqh, Wql, Wkh, Wkl, Wvh, Woh);

  qkv_kernel<<<dim3(16, 32, 3), 256, 0, stream>>>(xh, xl, Wqh, Wql, Wkh, Wkl, Wvh,
                                                  cosT, sinT, qh, kh, vt);

  attn_kernel<<<dim3(8, 32), 512, 0, stream>>>(qh, kh, vt, ch);

  out_kernel<<<dim3(16, 32), 256, 0, stream>>>(ch, Woh, out);
}

// Round 9
// 539.761 us; speedup vs baseline: 1.1064x; 1.0156x over previous
//
#include <hip/hip_runtime.h>

typedef unsigned short u16;
typedef __attribute__((ext_vector_type(8))) _Float16 f16x8;
typedef __attribute__((ext_vector_type(4))) float f32x4;

#define S_CTX 2048
#define DMODEL 2048

#define WAITVM(N) asm volatile("s_waitcnt vmcnt(" #N ")" ::: "memory")
#define SBAR() __builtin_amdgcn_s_barrier()

__device__ __forceinline__ u16 f2h(float f) {
  _Float16 h = (_Float16)f; u16 u; __builtin_memcpy(&u, &h, 2); return u;
}
__device__ __forceinline__ float h2f(u16 u) {
  _Float16 h; __builtin_memcpy(&h, &u, 2); return (float)h;
}
__device__ __forceinline__ void gload16(const u16* g, u16* l) {
  __builtin_amdgcn_global_load_lds(
      (const __attribute__((address_space(1))) unsigned int*)g,
      (__attribute__((address_space(3))) unsigned int*)l, 16, 0, 0);
}

// One fused split pass. x -> fp16 pair (no scale). Wq,Wk -> fp16 pair (x64).
// Wv,Wo -> fp16 single (x64). Scales folded out downstream (q-prescale, /4096).
__global__ void split_all(const float* __restrict__ x, const float* __restrict__ Wq,
                          const float* __restrict__ Wk, const float* __restrict__ Wv,
                          const float* __restrict__ Wo,
                          u16* xh, u16* xl, u16* Wqh, u16* Wql,
                          u16* Wkh, u16* Wkl, u16* Wvh, u16* Woh) {
  size_t i = (size_t)blockIdx.x * 256 + threadIdx.x;
  const size_t NX = 8388608, NW = 4194304;
  if (i < NX) {
    float v = x[i];
    u16 h = f2h(v);
    xh[i] = h; xl[i] = f2h(v - h2f(h));
  } else {
    size_t j = i - NX;
    int wsel = (int)(j >> 22);
    size_t o = j & (NW - 1);
    if (wsel == 0) { float v = Wq[o] * 64.f; u16 h = f2h(v); Wqh[o] = h; Wql[o] = f2h(v - h2f(h)); }
    else if (wsel == 1) { float v = Wk[o] * 64.f; u16 h = f2h(v); Wkh[o] = h; Wkl[o] = f2h(v - h2f(h)); }
    else if (wsel == 2) { Wvh[o] = f2h(Wv[o] * 64.f); }
    else { Woh[o] = f2h(Wo[o] * 64.f); }
  }
}

// ---------------------------------------------------------------------------
// C[M,N] = A * B^T, fp16 MFMA, 128x128 tile, 256 thr = 4 waves (2M x 2N),
// BK=32. Round-5 EXACT core (best measured: qkv 251 us): coalesced 16x64B-row
// staging + coalescing-neutral XOR chunk swizzle + counted-vmcnt pipeline.
// Identity block mapping (r6/r7 showed XCD remaps don't beat it in time).
//
//   NT==3: double-buffered (2 x 16K u16). Per K-step, 2 phases:
//     ph1: WAITVM(4) [h(t) landed]  SBAR  ds_read ah,bh  stage h(t+1)
//          16 MFMA (ah*bh)
//     ph2: WAITVM(4) [l(t) landed]  SBAR  ds_read bl,al  stage l(t+1)
//          32 MFMA (ah*bl, al*bh)
//     vmcnt oscillates 8 -> 4: never drained to 0 in the main loop.
//   NT==1: triple-buffered (3 x 8K u16), depth-2 prefetch, WAITVM(4)/step.
//
// NT==3: AhBh+AhBl+AlBh   NT==1: AhBh
// MODE 0: f32*oscale -> Cf
// MODE 2: V^T fp16 -> Ch  ([b][h][d][s])
// MODE 3: fused RoPE -> fp16 single Ch (tile = one full head; d<->d+64
//         exchanged through LDS per i-block; oscale folds the q prescale).
// ---------------------------------------------------------------------------
template <int NT, int MODE>
__device__ __forceinline__ void gemm_core(
    u16* sm, const u16* __restrict__ Am, const u16* __restrict__ Alm,
    const u16* __restrict__ Bm, const u16* __restrict__ Blm,
    float* __restrict__ Cf, u16* __restrict__ Ch,
    const float* __restrict__ cosT, const float* __restrict__ sinT,
    int N, int K, int m0, int n0, float oscale) {
  const int tid = threadIdx.x;
  const int w = tid >> 6, lane = tid & 63;
  const int quad = lane >> 4, l16 = lane & 15;
  const int wm = (w >> 1) << 6, wn = (w & 1) << 6;
  const int lrow = lane >> 2, lcol = (lane & 3) << 3;
  // source-side swizzle (u16 units): chunk ^= (row>>1)&3  (coalescing-neutral)
  const int lcs = lcol ^ (((lrow >> 1) & 3) << 3);
  // read-side swizzle: same involution
  const int qsw = (quad << 3) ^ (((l16 >> 1) & 3) << 3);

  // stage h-parts (Ah,Bh) of one K-tile into buffer at base bufb (u16 units)
  auto stageH = [&](int bufb, int k0) {
#pragma unroll
    for (int j = 0; j < 2; ++j) {
      int r = w * 32 + j * 16 + lrow;
      int lb = bufb + (w * 32 + j * 16) * 32;
      size_t ga = (size_t)(m0 + r) * K + k0 + lcs;
      size_t gb = (size_t)(n0 + r) * K + k0 + lcs;
      gload16(Am + ga, &sm[lb]);
      gload16(Bm + gb, &sm[lb + 4096]);
    }
  };
  // stage l-parts (Bl,Al)
  auto stageL = [&](int bufb, int k0) {
#pragma unroll
    for (int j = 0; j < 2; ++j) {
      int r = w * 32 + j * 16 + lrow;
      int lb = bufb + (w * 32 + j * 16) * 32;
      size_t ga = (size_t)(m0 + r) * K + k0 + lcs;
      size_t gb = (size_t)(n0 + r) * K + k0 + lcs;
      gload16(Blm + gb, &sm[lb + 8192]);
      gload16(Alm + ga, &sm[lb + 12288]);
    }
  };

  f32x4 acc[4][4];
#pragma unroll
  for (int i = 0; i < 4; ++i)
#pragma unroll
    for (int n = 0; n < 4; ++n) acc[i][n] = (f32x4){0.f, 0.f, 0.f, 0.f};

  const int NTL = K >> 5;

  if (NT == 3) {
    stageH(0, 0);   // 4 loads
    stageL(0, 0);   // 4 loads -> 8 outstanding
    for (int t = 0; t < NTL; ++t) {
      const int cur = (t & 1) << 14;      // 0 / 16384
      const int nxt = 16384 - cur;
      const int k0n = (t + 1) << 5;
      const bool more = (t + 1 < NTL);

      // ---- phase 1: Ah x Bh ----
      WAITVM(4);    // h(t) landed (l(t) stays in flight)
      SBAR();
      f16x8 ah[4], bh[4];
#pragma unroll
      for (int i = 0; i < 4; ++i)
        ah[i] = *(const f16x8*)&sm[cur + (wm + i * 16 + l16) * 32 + qsw];
#pragma unroll
      for (int n = 0; n < 4; ++n)
        bh[n] = *(const f16x8*)&sm[cur + 4096 + (wn + n * 16 + l16) * 32 + qsw];
      if (more) stageH(nxt, k0n);
#pragma unroll
      for (int i = 0; i < 4; ++i)
#pragma unroll
        for (int n = 0; n < 4; ++n)
          acc[i][n] = __builtin_amdgcn_mfma_f32_16x16x32_f16(ah[i], bh[n], acc[i][n], 0, 0, 0);

      // ---- phase 2: Ah x Bl + Al x Bh ----
      if (more) { WAITVM(4); } else { WAITVM(0); }  // l(t) landed
      SBAR();
      f16x8 bl[4], al[4];
#pragma unroll
      for (int n = 0; n < 4; ++n)
        bl[n] = *(const f16x8*)&sm[cur + 8192 + (wn + n * 16 + l16) * 32 + qsw];
#pragma unroll
      for (int i = 0; i < 4; ++i)
        al[i] = *(const f16x8*)&sm[cur + 12288 + (wm + i * 16 + l16) * 32 + qsw];
      if (more) stageL(nxt, k0n);
#pragma unroll
      for (int i = 0; i < 4; ++i)
#pragma unroll
        for (int n = 0; n < 4; ++n) {
          acc[i][n] = __builtin_amdgcn_mfma_f32_16x16x32_f16(ah[i], bl[n], acc[i][n], 0, 0, 0);
          acc[i][n] = __builtin_amdgcn_mfma_f32_16x16x32_f16(al[i], bh[n], acc[i][n], 0, 0, 0);
        }
    }
  } else {
    stageH(0, 0);       // tile 0
    stageH(8192, 32);   // tile 1 -> 8 outstanding
    for (int t = 0; t < NTL; ++t) {
      const int cur = (t % 3) * 8192;
      if (t + 1 < NTL) { WAITVM(4); } else { WAITVM(0); }  // tile t landed
      SBAR();
      f16x8 ah[4], bh[4];
#pragma unroll
      for (int i = 0; i < 4; ++i)
        ah[i] = *(const f16x8*)&sm[cur + (wm + i * 16 + l16) * 32 + qsw];
#pragma unroll
      for (int n = 0; n < 4; ++n)
        bh[n] = *(const f16x8*)&sm[cur + 4096 + (wn + n * 16 + l16) * 32 + qsw];
      if (t + 2 < NTL) stageH(((t + 2) % 3) * 8192, (t + 2) << 5);
#pragma unroll
      for (int i = 0; i < 4; ++i)
#pragma unroll
        for (int n = 0; n < 4; ++n)
          acc[i][n] = __builtin_amdgcn_mfma_f32_16x16x32_f16(ah[i], bh[n], acc[i][n], 0, 0, 0);
    }
  }

  // epilogue: C/D layout row=(lane>>4)*4+r, col=lane&15
  if (MODE == 3) {
    // fused RoPE: tile cols n0..n0+127 are exactly one head (d = local col).
    float* fs = (float*)sm;  // 2 pairs x 16 rows x 128 cols f32 = 16 KiB
    const int p = w >> 1;
#pragma unroll
    for (int i = 0; i < 4; ++i) {
      __syncthreads();  // prev i-block reads (or K-loop LDS reads) done
#pragma unroll
      for (int n = 0; n < 4; ++n)
#pragma unroll
        for (int r = 0; r < 4; ++r)
          fs[p * 2048 + (quad * 4 + r) * 128 + wn + n * 16 + l16] = acc[i][n][r];
      __syncthreads();
#pragma unroll
      for (int n = 0; n < 4; ++n) {
        const int col = wn + n * 16 + l16;
        const int cc = col ^ 64;
        const float sgn = (col < 64) ? -1.f : 1.f;
#pragma unroll
        for (int r = 0; r < 4; ++r) {
          const int row16 = quad * 4 + r;
          const int grow = m0 + wm + i * 16 + row16;
          const int s = grow & (S_CTX - 1);
          const float c = cosT[s * 128 + col];
          const float sn = sinT[s * 128 + col];
          const float x = fs[p * 2048 + row16 * 128 + col];
          const float xp = fs[p * 2048 + row16 * 128 + cc];
          Ch[(size_t)grow * N + n0 + col] = f2h((x * c + sgn * xp * sn) * oscale);
        }
      }
    }
    return;
  }
#pragma unroll
  for (int i = 0; i < 4; ++i)
#pragma unroll
    for (int n = 0; n < 4; ++n) {
      const int row0 = m0 + wm + i * 16 + quad * 4;
      const int col = n0 + wn + n * 16 + l16;
      if (MODE == 0) {
#pragma unroll
        for (int r = 0; r < 4; ++r) Cf[(size_t)(row0 + r) * N + col] = acc[i][n][r] * oscale;
      } else {
        int brow = row0 >> 11, s0 = row0 & 2047;
        int hh = col >> 7, d = col & 127;
        ushort4 pk;
        pk.x = f2h(acc[i][n][0]);
        pk.y = f2h(acc[i][n][1]);
        pk.z = f2h(acc[i][n][2]);
        pk.w = f2h(acc[i][n][3]);
        *(ushort4*)(Ch + ((size_t)(brow * 16 + hh) * 128 + d) * 2048 + s0) = pk;
      }
    }
}

// Fused QKV projection + RoPE: grid (16, 32, 3).
// z=0: Q (3-term, rope + qs prescale); z=1: K (3-term, rope); z=2: V (1-term, V^T out)
__global__ __launch_bounds__(256) void qkv_kernel(
    const u16* __restrict__ xh, const u16* __restrict__ xl,
    const u16* __restrict__ Wqh, const u16* __restrict__ Wql,
    const u16* __restrict__ Wkh, const u16* __restrict__ Wkl,
    const u16* __restrict__ Wvh,
    const float* __restrict__ cosT, const float* __restrict__ sinT,
    u16* qh, u16* kh, u16* vt) {
  __shared__ u16 sm[32768];  // 64 KiB: 2 x 16K u16 (NT3 dbuf) / 3 x 8K (NT1)
  const int m0 = blockIdx.y << 7, n0 = blockIdx.x << 7;
  const float qs = 0.002762135864009951f;  // sqrt(128)/4096
  if (blockIdx.z == 0)
    gemm_core<3, 3>(sm, xh, xl, Wqh, Wql, nullptr, qh, cosT, sinT, DMODEL, DMODEL, m0, n0, qs);
  else if (blockIdx.z == 1)
    gemm_core<3, 3>(sm, xh, xl, Wkh, Wkl, nullptr, kh, cosT, sinT, DMODEL, DMODEL, m0, n0, 1.f);
  else
    gemm_core<1, 2>(sm, xh, nullptr, Wvh, nullptr, nullptr, vt, nullptr, nullptr, DMODEL, DMODEL, m0, n0, 1.f);
}

// out = (ch * Woh^T) / 4096  (1-term fp16; dropped terms ~1.5e-4)
__global__ __launch_bounds__(256) void out_kernel(
    const u16* __restrict__ ch, const u16* __restrict__ Woh, float* __restrict__ out) {
  __shared__ u16 sm[24576];  // 48 KiB: 3 x 8K u16
  gemm_core<1, 0>(sm, ch, nullptr, Woh, nullptr, out, nullptr, nullptr, nullptr, DMODEL, DMODEL,
                  blockIdx.y << 7, blockIdx.x << 7, 1.f / 4096.f);
}

// Flash attention, causal. 1-term fp16 QK (q pre-scaled), f32 online softmax,
// fp16 P and PV with V^T [b][h][d][s]. BQ=128: 512 thr = 8 waves x 16 q-rows
// sharing K/V tiles (BK=64). 2 barriers/iter; reg prefetch of tile kt+1.
// Swapped QK^T (r8): lane-local softmax rows, 4 shfl/step.
//
// Round 9 — BALANCED PAIRS + 2 BLOCKS/CU: 512 blocks, ONE q-tile each.
// lin<256 -> qt = 15-(lin&7) (heavy, dispatched first); lin>=256 -> qt =
// lin&7 (light). Blocks c and c+256 share a CU (r5-verified dispatch
// property) -> per-CU steps = 34 for every CU, AND two independent 8-wave
// blocks co-resident: one block's barrier/staging stalls overlap the
// other's MFMA (m114). __launch_bounds__(512,4) = 4 waves/EU = 16 waves/CU
// caps VGPR at 128 so co-residency is guaranteed. LDS 52KB x 2 = 104KB.
// Per-q-tile math unchanged -> bit-identical output.
__global__ __launch_bounds__(512, 4) void attn_kernel(
    const u16* __restrict__ Qh, const u16* __restrict__ Kh,
    const u16* __restrict__ VT, u16* __restrict__ Ch) {
  const int lin = blockIdx.x | (blockIdx.y << 4);  // 0..511
  const int pair = lin & 255;
  const int bh = pair >> 3;
  const int q8 = pair & 7;
  const int qt = (lin < 256) ? (15 - q8) : q8;
  const int b = bh >> 4, h = bh & 15;
  const int tid = threadIdx.x;
  const int w = tid >> 6, lane = tid & 63;
  const int quad = lane >> 4, l16 = lane & 15;

  __shared__ u16 sKh[64 * 136];   // K-tile [k][d] pitch 136
  __shared__ u16 sVt[128 * 72];   // V^T tile [d][k], pitch 72
  __shared__ u16 sPb[8 * 1088];   // per-wave P, 16 x 68 each (dedicated)
  u16* sP = &sPb[w * 1088];

  const size_t bhbase = (size_t)b * S_CTX * DMODEL + (size_t)h * 128;
  const size_t vtbase = (size_t)bh * 128 * 2048;

  int kr[2], kc[2], vr[2], vc[2];
#pragma unroll
  for (int j = 0; j < 2; ++j) {
    int c = j * 512 + tid;
    kr[j] = c >> 4; kc[j] = (c & 15) << 3;
    vr[j] = c >> 3; vc[j] = (c & 7) << 3;
  }

  // Q fragments; wave w owns q-rows qt*128 + w*16 + [0,16)
  const int qr0 = qt * 128 + w * 16;
  const size_t qoff = bhbase + (size_t)(qr0 + l16) * DMODEL;
  f16x8 qf[4];
#pragma unroll
  for (int c = 0; c < 4; ++c) qf[c] = *(const f16x8*)(Qh + qoff + c * 32 + quad * 8);

  f32x4 oacc[8];
#pragma unroll
  for (int d = 0; d < 8; ++d) oacc[d] = (f32x4){0.f, 0.f, 0.f, 0.f};
  float m_r = -INFINITY;  // running max for q-row qr0 + l16
  float l_r = 0.f;        // running denom for q-row qr0 + l16

  f16x8 rkh[2], rvt[2];
#pragma unroll
  for (int j = 0; j < 2; ++j) {
    rkh[j] = *(const f16x8*)(Kh + bhbase + (size_t)kr[j] * DMODEL + kc[j]);
    rvt[j] = *(const f16x8*)(VT + vtbase + (size_t)vr[j] * 2048 + vc[j]);
  }

  const int nkt = 2 * qt + 2;
  for (int kt = 0; kt < nkt; ++kt) {
    __syncthreads();  // (1) prev iter LDS reads done
#pragma unroll
    for (int j = 0; j < 2; ++j) {
      *(f16x8*)&sKh[kr[j] * 136 + kc[j]] = rkh[j];
      *(f16x8*)&sVt[vr[j] * 72 + vc[j]] = rvt[j];
    }
    __syncthreads();  // (2) tiles visible
    if (kt + 1 < nkt) {
#pragma unroll
      for (int j = 0; j < 2; ++j) {
        size_t g = bhbase + (size_t)((kt + 1) * 64 + kr[j]) * DMODEL + kc[j];
        rkh[j] = *(const f16x8*)(Kh + g);
        rvt[j] = *(const f16x8*)(VT + vtbase + (size_t)vr[j] * 2048 + (kt + 1) * 64 + vc[j]);
      }
    }

    const bool active = (kt * 64) <= (qr0 + 15);
    if (active) {
      f32x4 sacc[4];
#pragma unroll
      for (int n = 0; n < 4; ++n) sacc[n] = (f32x4){0.f, 0.f, 0.f, 0.f};
      __builtin_amdgcn_s_setprio(1);
#pragma unroll
      for (int n = 0; n < 4; ++n)
#pragma unroll
        for (int c = 0; c < 4; ++c) {
          f16x8 kf = *(const f16x8*)&sKh[(n * 16 + l16) * 136 + c * 32 + quad * 8];
          sacc[n] = __builtin_amdgcn_mfma_f32_16x16x32_f16(kf, qf[c], sacc[n], 0, 0, 0);
        }
      __builtin_amdgcn_s_setprio(0);

      // thread's q-row: qi = qr0 + l16; score k = kt*64 + n*16 + quad*4 + r
      const int qi = qr0 + l16;
      const int kb = kt * 64 + quad * 4;
      float pm[4][4];
      float rmax = -INFINITY;
#pragma unroll
      for (int n = 0; n < 4; ++n)
#pragma unroll
        for (int r = 0; r < 4; ++r) {
          float sc = sacc[n][r];
          if (kb + n * 16 + r > qi) sc = -INFINITY;
          pm[n][r] = sc;
          rmax = fmaxf(rmax, sc);
        }
      rmax = fmaxf(rmax, __shfl_xor(rmax, 16, 64));
      rmax = fmaxf(rmax, __shfl_xor(rmax, 32, 64));

      const float mnew = fmaxf(m_r, rmax);
      const float alpha = __expf(m_r - mnew);
      m_r = mnew;
      l_r *= alpha;
      float rsum = 0.f;
#pragma unroll
      for (int n = 0; n < 4; ++n)
#pragma unroll
        for (int r = 0; r < 4; ++r) {
          float pv = __expf(pm[n][r] - m_r);
          pm[n][r] = pv;
          rsum += pv;
        }
      rsum += __shfl_xor(rsum, 16, 64);
      rsum += __shfl_xor(rsum, 32, 64);
      l_r += rsum;

      // redistribute alpha to PV C-layout rows (quad*4 + r)
      float apv[4];
#pragma unroll
      for (int r = 0; r < 4; ++r)
        apv[r] = __shfl(alpha, (lane & 48) | (quad * 4 + r), 64);
#pragma unroll
      for (int d = 0; d < 8; ++d)
#pragma unroll
        for (int r = 0; r < 4; ++r) oacc[d][r] *= apv[r];

      // P -> per-wave LDS (A-layout row = q-local l16), packed ushort4
#pragma unroll
      for (int n = 0; n < 4; ++n) {
        ushort4 pk;
        pk.x = f2h(pm[n][0]);
        pk.y = f2h(pm[n][1]);
        pk.z = f2h(pm[n][2]);
        pk.w = f2h(pm[n][3]);
        *(ushort4*)&sP[l16 * 68 + n * 16 + quad * 4] = pk;
      }

      // O += P.V
      __builtin_amdgcn_s_setprio(1);
#pragma unroll
      for (int c = 0; c < 2; ++c) {
        f16x8 pf = *(const f16x8*)&sP[l16 * 68 + c * 32 + quad * 8];
#pragma unroll
        for (int d = 0; d < 8; ++d) {
          f16x8 vf = *(const f16x8*)&sVt[(d * 16 + l16) * 72 + c * 32 + quad * 8];
          oacc[d] = __builtin_amdgcn_mfma_f32_16x16x32_f16(pf, vf, oacc[d], 0, 0, 0);
        }
      }
      __builtin_amdgcn_s_setprio(0);
    }
  }

  const float invl = 1.f / l_r;
  float ipv[4];
#pragma unroll
  for (int r = 0; r < 4; ++r)
    ipv[r] = __shfl(invl, (lane & 48) | (quad * 4 + r), 64);
#pragma unroll
  for (int d = 0; d < 8; ++d)
#pragma unroll
    for (int r = 0; r < 4; ++r) {
      int row = qr0 + quad * 4 + r;
      Ch[bhbase + (size_t)row * DMODEL + d * 16 + l16] = f2h(oacc[d][r] * ipv[r]);
    }
}

extern "C" void kernel_launch(void* const* d_in, const int* in_sizes, int n_in,
                              void* d_out, int out_size, void* d_ws, size_t ws_size,
                              hipStream_t stream) {
  const float* x    = (const float*)d_in[0];
  const float* Wq   = (const float*)d_in[1];
  const float* Wk   = (const float*)d_in[2];
  const float* Wv   = (const float*)d_in[3];
  const float* Wo   = (const float*)d_in[4];
  const float* cosT = (const float*)d_in[5];
  const float* sinT = (const float*)d_in[6];
  float* out = (float*)d_out;

  const size_t NX = 8388608;   // 2*2048*2048
  const size_t NW = 4194304;   // 2048*2048
  u16* p = (u16*)d_ws;
  u16* xh  = p; p += NX;  u16* xl  = p; p += NX;
  u16* Wqh = p; p += NW;  u16* Wql = p; p += NW;
  u16* Wkh = p; p += NW;  u16* Wkl = p; p += NW;
  u16* Wvh = p; p += NW;  u16* Woh = p; p += NW;
  u16* qh  = p; p += NX;  u16* kh  = p; p += NX;
  u16* vt  = p; p += NX;
  u16* ch  = p; p += NX;
  // ~150 MiB of d_ws

  split_all<<<98304, 256, 0, stream>>>(x, Wq, Wk, Wv, Wo,
                                       xh, xl, Wqh, Wql, Wkh, Wkl, Wvh, Woh);

  qkv_kernel<<<dim3(16, 32, 3), 256, 0, stream>>>(xh, xl, Wqh, Wql, Wkh, Wkl, Wvh,
                                                  cosT, sinT, qh, kh, vt);

  attn_kernel<<<dim3(16, 32), 512, 0, stream>>>(qh, kh, vt, ch);

  out_kernel<<<dim3(16, 32), 256, 0, stream>>>(ch, Woh, out);
}

// Round 10
// 537.857 us; speedup vs baseline: 1.1103x; 1.0035x over previous
//
#include <hip/hip_runtime.h>

typedef unsigned short u16;
typedef __attribute__((ext_vector_type(8))) _Float16 f16x8;
typedef __attribute__((ext_vector_type(4))) float f32x4;

#define S_CTX 2048
#define DMODEL 2048

#define WAITVM(N) asm volatile("s_waitcnt vmcnt(" #N ")" ::: "memory")
#define SBAR() __builtin_amdgcn_s_barrier()

__device__ __forceinline__ u16 f2h(float f) {
  _Float16 h = (_Float16)f; u16 u; __builtin_memcpy(&u, &h, 2); return u;
}
__device__ __forceinline__ float h2f(u16 u) {
  _Float16 h; __builtin_memcpy(&h, &u, 2); return (float)h;
}
__device__ __forceinline__ void gload16(const u16* g, u16* l) {
  __builtin_amdgcn_global_load_lds(
      (const __attribute__((address_space(1))) unsigned int*)g,
      (__attribute__((address_space(3))) unsigned int*)l, 16, 0, 0);
}

// One fused split pass. x -> fp16 pair (no scale). Wq,Wk -> fp16 pair (x64).
// Wv,Wo -> fp16 single (x64). Scales folded out downstream (q-prescale, /4096).
__global__ void split_all(const float* __restrict__ x, const float* __restrict__ Wq,
                          const float* __restrict__ Wk, const float* __restrict__ Wv,
                          const float* __restrict__ Wo,
                          u16* xh, u16* xl, u16* Wqh, u16* Wql,
                          u16* Wkh, u16* Wkl, u16* Wvh, u16* Woh) {
  size_t i = (size_t)blockIdx.x * 256 + threadIdx.x;
  const size_t NX = 8388608, NW = 4194304;
  if (i < NX) {
    float v = x[i];
    u16 h = f2h(v);
    xh[i] = h; xl[i] = f2h(v - h2f(h));
  } else {
    size_t j = i - NX;
    int wsel = (int)(j >> 22);
    size_t o = j & (NW - 1);
    if (wsel == 0) { float v = Wq[o] * 64.f; u16 h = f2h(v); Wqh[o] = h; Wql[o] = f2h(v - h2f(h)); }
    else if (wsel == 1) { float v = Wk[o] * 64.f; u16 h = f2h(v); Wkh[o] = h; Wkl[o] = f2h(v - h2f(h)); }
    else if (wsel == 2) { Wvh[o] = f2h(Wv[o] * 64.f); }
    else { Woh[o] = f2h(Wo[o] * 64.f); }
  }
}

// ---------------------------------------------------------------------------
// C[M,N] = A * B^T, fp16 MFMA, 128x128 tile, 256 thr = 4 waves (2M x 2N),
// BK=32. Round-5 EXACT core (best measured): coalesced 16x64B-row staging +
// coalescing-neutral XOR chunk swizzle + counted-vmcnt pipeline.
//
//   NT==3: double-buffered (2 x 16K u16). Per K-step, 2 phases:
//     ph1: WAITVM(4) [h(t) landed]  SBAR  ds_read ah,bh  stage h(t+1)
//          16 MFMA (ah*bh)
//     ph2: WAITVM(4) [l(t) landed]  SBAR  ds_read bl,al  stage l(t+1)
//          32 MFMA (ah*bl, al*bh)
//     vmcnt oscillates 8 -> 4: never drained to 0 in the main loop.
//   NT==1: triple-buffered (3 x 8K u16), depth-2 prefetch, WAITVM(4)/step.
//
// NT==3: AhBh+AhBl+AlBh   NT==1: AhBh
// MODE 0: f32*oscale -> Cf
// MODE 2: V^T fp16 -> Ch  ([b][h][d][s])
// MODE 3: fused RoPE -> fp16 single Ch (tile = one full head; d<->d+64
//         exchanged through LDS per i-block; oscale folds the q prescale).
// ---------------------------------------------------------------------------
template <int NT, int MODE>
__device__ __forceinline__ void gemm_core(
    u16* sm, const u16* __restrict__ Am, const u16* __restrict__ Alm,
    const u16* __restrict__ Bm, const u16* __restrict__ Blm,
    float* __restrict__ Cf, u16* __restrict__ Ch,
    const float* __restrict__ cosT, const float* __restrict__ sinT,
    int N, int K, int m0, int n0, float oscale) {
  const int tid = threadIdx.x;
  const int w = tid >> 6, lane = tid & 63;
  const int quad = lane >> 4, l16 = lane & 15;
  const int wm = (w >> 1) << 6, wn = (w & 1) << 6;
  const int lrow = lane >> 2, lcol = (lane & 3) << 3;
  // source-side swizzle (u16 units): chunk ^= (row>>1)&3  (coalescing-neutral)
  const int lcs = lcol ^ (((lrow >> 1) & 3) << 3);
  // read-side swizzle: same involution
  const int qsw = (quad << 3) ^ (((l16 >> 1) & 3) << 3);

  // stage h-parts (Ah,Bh) of one K-tile into buffer at base bufb (u16 units)
  auto stageH = [&](int bufb, int k0) {
#pragma unroll
    for (int j = 0; j < 2; ++j) {
      int r = w * 32 + j * 16 + lrow;
      int lb = bufb + (w * 32 + j * 16) * 32;
      size_t ga = (size_t)(m0 + r) * K + k0 + lcs;
      size_t gb = (size_t)(n0 + r) * K + k0 + lcs;
      gload16(Am + ga, &sm[lb]);
      gload16(Bm + gb, &sm[lb + 4096]);
    }
  };
  // stage l-parts (Bl,Al)
  auto stageL = [&](int bufb, int k0) {
#pragma unroll
    for (int j = 0; j < 2; ++j) {
      int r = w * 32 + j * 16 + lrow;
      int lb = bufb + (w * 32 + j * 16) * 32;
      size_t ga = (size_t)(m0 + r) * K + k0 + lcs;
      size_t gb = (size_t)(n0 + r) * K + k0 + lcs;
      gload16(Blm + gb, &sm[lb + 8192]);
      gload16(Alm + ga, &sm[lb + 12288]);
    }
  };

  f32x4 acc[4][4];
#pragma unroll
  for (int i = 0; i < 4; ++i)
#pragma unroll
    for (int n = 0; n < 4; ++n) acc[i][n] = (f32x4){0.f, 0.f, 0.f, 0.f};

  const int NTL = K >> 5;

  if (NT == 3) {
    stageH(0, 0);   // 4 loads
    stageL(0, 0);   // 4 loads -> 8 outstanding
    for (int t = 0; t < NTL; ++t) {
      const int cur = (t & 1) << 14;      // 0 / 16384
      const int nxt = 16384 - cur;
      const int k0n = (t + 1) << 5;
      const bool more = (t + 1 < NTL);

      // ---- phase 1: Ah x Bh ----
      WAITVM(4);    // h(t) landed (l(t) stays in flight)
      SBAR();
      f16x8 ah[4], bh[4];
#pragma unroll
      for (int i = 0; i < 4; ++i)
        ah[i] = *(const f16x8*)&sm[cur + (wm + i * 16 + l16) * 32 + qsw];
#pragma unroll
      for (int n = 0; n < 4; ++n)
        bh[n] = *(const f16x8*)&sm[cur + 4096 + (wn + n * 16 + l16) * 32 + qsw];
      if (more) stageH(nxt, k0n);
#pragma unroll
      for (int i = 0; i < 4; ++i)
#pragma unroll
        for (int n = 0; n < 4; ++n)
          acc[i][n] = __builtin_amdgcn_mfma_f32_16x16x32_f16(ah[i], bh[n], acc[i][n], 0, 0, 0);

      // ---- phase 2: Ah x Bl + Al x Bh ----
      if (more) { WAITVM(4); } else { WAITVM(0); }  // l(t) landed
      SBAR();
      f16x8 bl[4], al[4];
#pragma unroll
      for (int n = 0; n < 4; ++n)
        bl[n] = *(const f16x8*)&sm[cur + 8192 + (wn + n * 16 + l16) * 32 + qsw];
#pragma unroll
      for (int i = 0; i < 4; ++i)
        al[i] = *(const f16x8*)&sm[cur + 12288 + (wm + i * 16 + l16) * 32 + qsw];
      if (more) stageL(nxt, k0n);
#pragma unroll
      for (int i = 0; i < 4; ++i)
#pragma unroll
        for (int n = 0; n < 4; ++n) {
          acc[i][n] = __builtin_amdgcn_mfma_f32_16x16x32_f16(ah[i], bl[n], acc[i][n], 0, 0, 0);
          acc[i][n] = __builtin_amdgcn_mfma_f32_16x16x32_f16(al[i], bh[n], acc[i][n], 0, 0, 0);
        }
    }
  } else {
    stageH(0, 0);       // tile 0
    stageH(8192, 32);   // tile 1 -> 8 outstanding
    for (int t = 0; t < NTL; ++t) {
      const int cur = (t % 3) * 8192;
      if (t + 1 < NTL) { WAITVM(4); } else { WAITVM(0); }  // tile t landed
      SBAR();
      f16x8 ah[4], bh[4];
#pragma unroll
      for (int i = 0; i < 4; ++i)
        ah[i] = *(const f16x8*)&sm[cur + (wm + i * 16 + l16) * 32 + qsw];
#pragma unroll
      for (int n = 0; n < 4; ++n)
        bh[n] = *(const f16x8*)&sm[cur + 4096 + (wn + n * 16 + l16) * 32 + qsw];
      if (t + 2 < NTL) stageH(((t + 2) % 3) * 8192, (t + 2) << 5);
#pragma unroll
      for (int i = 0; i < 4; ++i)
#pragma unroll
        for (int n = 0; n < 4; ++n)
          acc[i][n] = __builtin_amdgcn_mfma_f32_16x16x32_f16(ah[i], bh[n], acc[i][n], 0, 0, 0);
    }
  }

  // epilogue: C/D layout row=(lane>>4)*4+r, col=lane&15
  if (MODE == 3) {
    // fused RoPE: tile cols n0..n0+127 are exactly one head (d = local col).
    float* fs = (float*)sm;  // 2 pairs x 16 rows x 128 cols f32 = 16 KiB
    const int p = w >> 1;
#pragma unroll
    for (int i = 0; i < 4; ++i) {
      __syncthreads();  // prev i-block reads (or K-loop LDS reads) done
#pragma unroll
      for (int n = 0; n < 4; ++n)
#pragma unroll
        for (int r = 0; r < 4; ++r)
          fs[p * 2048 + (quad * 4 + r) * 128 + wn + n * 16 + l16] = acc[i][n][r];
      __syncthreads();
#pragma unroll
      for (int n = 0; n < 4; ++n) {
        const int col = wn + n * 16 + l16;
        const int cc = col ^ 64;
        const float sgn = (col < 64) ? -1.f : 1.f;
#pragma unroll
        for (int r = 0; r < 4; ++r) {
          const int row16 = quad * 4 + r;
          const int grow = m0 + wm + i * 16 + row16;
          const int s = grow & (S_CTX - 1);
          const float c = cosT[s * 128 + col];
          const float sn = sinT[s * 128 + col];
          const float x = fs[p * 2048 + row16 * 128 + col];
          const float xp = fs[p * 2048 + row16 * 128 + cc];
          Ch[(size_t)grow * N + n0 + col] = f2h((x * c + sgn * xp * sn) * oscale);
        }
      }
    }
    return;
  }
#pragma unroll
  for (int i = 0; i < 4; ++i)
#pragma unroll
    for (int n = 0; n < 4; ++n) {
      const int row0 = m0 + wm + i * 16 + quad * 4;
      const int col = n0 + wn + n * 16 + l16;
      if (MODE == 0) {
#pragma unroll
        for (int r = 0; r < 4; ++r) Cf[(size_t)(row0 + r) * N + col] = acc[i][n][r] * oscale;
      } else {
        int brow = row0 >> 11, s0 = row0 & 2047;
        int hh = col >> 7, d = col & 127;
        ushort4 pk;
        pk.x = f2h(acc[i][n][0]);
        pk.y = f2h(acc[i][n][1]);
        pk.z = f2h(acc[i][n][2]);
        pk.w = f2h(acc[i][n][3]);
        *(ushort4*)(Ch + ((size_t)(brow * 16 + hh) * 128 + d) * 2048 + s0) = pk;
      }
    }
}

// Round 10: qkv split into three kernels (same per-block work as the r9
// z-slices; z was already the slowest-varying dispatch dim, so this changes
// scheduling only at two kernel boundaries). Purpose: the top-5 dispatch
// table can now surface attn/out counters (they were always hidden behind
// the 255 us fused qkv).
__global__ __launch_bounds__(256) void q_kernel(
    const u16* __restrict__ xh, const u16* __restrict__ xl,
    const u16* __restrict__ Wqh, const u16* __restrict__ Wql,
    const float* __restrict__ cosT, const float* __restrict__ sinT,
    u16* qh) {
  __shared__ u16 sm[32768];
  const float qs = 0.002762135864009951f;  // sqrt(128)/4096
  gemm_core<3, 3>(sm, xh, xl, Wqh, Wql, nullptr, qh, cosT, sinT, DMODEL, DMODEL,
                  blockIdx.y << 7, blockIdx.x << 7, qs);
}

__global__ __launch_bounds__(256) void k_kernel(
    const u16* __restrict__ xh, const u16* __restrict__ xl,
    const u16* __restrict__ Wkh, const u16* __restrict__ Wkl,
    const float* __restrict__ cosT, const float* __restrict__ sinT,
    u16* kh) {
  __shared__ u16 sm[32768];
  gemm_core<3, 3>(sm, xh, xl, Wkh, Wkl, nullptr, kh, cosT, sinT, DMODEL, DMODEL,
                  blockIdx.y << 7, blockIdx.x << 7, 1.f);
}

__global__ __launch_bounds__(256) void v_kernel(
    const u16* __restrict__ xh, const u16* __restrict__ Wvh, u16* vt) {
  __shared__ u16 sm[24576];
  gemm_core<1, 2>(sm, xh, nullptr, Wvh, nullptr, nullptr, vt, nullptr, nullptr,
                  DMODEL, DMODEL, blockIdx.y << 7, blockIdx.x << 7, 1.f);
}

// out = (ch * Woh^T) / 4096  (1-term fp16; dropped terms ~1.5e-4)
__global__ __launch_bounds__(256) void out_kernel(
    const u16* __restrict__ ch, const u16* __restrict__ Woh, float* __restrict__ out) {
  __shared__ u16 sm[24576];  // 48 KiB: 3 x 8K u16
  gemm_core<1, 0>(sm, ch, nullptr, Woh, nullptr, out, nullptr, nullptr, nullptr, DMODEL, DMODEL,
                  blockIdx.y << 7, blockIdx.x << 7, 1.f / 4096.f);
}

// Flash attention, causal — round-9 state (balanced pairs + 2 blocks/CU,
// swapped QK^T lane-local softmax). Unchanged this round.
__global__ __launch_bounds__(512, 4) void attn_kernel(
    const u16* __restrict__ Qh, const u16* __restrict__ Kh,
    const u16* __restrict__ VT, u16* __restrict__ Ch) {
  const int lin = blockIdx.x | (blockIdx.y << 4);  // 0..511
  const int pair = lin & 255;
  const int bh = pair >> 3;
  const int q8 = pair & 7;
  const int qt = (lin < 256) ? (15 - q8) : q8;
  const int b = bh >> 4, h = bh & 15;
  const int tid = threadIdx.x;
  const int w = tid >> 6, lane = tid & 63;
  const int quad = lane >> 4, l16 = lane & 15;

  __shared__ u16 sKh[64 * 136];   // K-tile [k][d] pitch 136
  __shared__ u16 sVt[128 * 72];   // V^T tile [d][k], pitch 72
  __shared__ u16 sPb[8 * 1088];   // per-wave P, 16 x 68 each (dedicated)
  u16* sP = &sPb[w * 1088];

  const size_t bhbase = (size_t)b * S_CTX * DMODEL + (size_t)h * 128;
  const size_t vtbase = (size_t)bh * 128 * 2048;

  int kr[2], kc[2], vr[2], vc[2];
#pragma unroll
  for (int j = 0; j < 2; ++j) {
    int c = j * 512 + tid;
    kr[j] = c >> 4; kc[j] = (c & 15) << 3;
    vr[j] = c >> 3; vc[j] = (c & 7) << 3;
  }

  // Q fragments; wave w owns q-rows qt*128 + w*16 + [0,16)
  const int qr0 = qt * 128 + w * 16;
  const size_t qoff = bhbase + (size_t)(qr0 + l16) * DMODEL;
  f16x8 qf[4];
#pragma unroll
  for (int c = 0; c < 4; ++c) qf[c] = *(const f16x8*)(Qh + qoff + c * 32 + quad * 8);

  f32x4 oacc[8];
#pragma unroll
  for (int d = 0; d < 8; ++d) oacc[d] = (f32x4){0.f, 0.f, 0.f, 0.f};
  float m_r = -INFINITY;  // running max for q-row qr0 + l16
  float l_r = 0.f;        // running denom for q-row qr0 + l16

  f16x8 rkh[2], rvt[2];
#pragma unroll
  for (int j = 0; j < 2; ++j) {
    rkh[j] = *(const f16x8*)(Kh + bhbase + (size_t)kr[j] * DMODEL + kc[j]);
    rvt[j] = *(const f16x8*)(VT + vtbase + (size_t)vr[j] * 2048 + vc[j]);
  }

  const int nkt = 2 * qt + 2;
  for (int kt = 0; kt < nkt; ++kt) {
    __syncthreads();  // (1) prev iter LDS reads done
#pragma unroll
    for (int j = 0; j < 2; ++j) {
      *(f16x8*)&sKh[kr[j] * 136 + kc[j]] = rkh[j];
      *(f16x8*)&sVt[vr[j] * 72 + vc[j]] = rvt[j];
    }
    __syncthreads();  // (2) tiles visible
    if (kt + 1 < nkt) {
#pragma unroll
      for (int j = 0; j < 2; ++j) {
        size_t g = bhbase + (size_t)((kt + 1) * 64 + kr[j]) * DMODEL + kc[j];
        rkh[j] = *(const f16x8*)(Kh + g);
        rvt[j] = *(const f16x8*)(VT + vtbase + (size_t)vr[j] * 2048 + (kt + 1) * 64 + vc[j]);
      }
    }

    const bool active = (kt * 64) <= (qr0 + 15);
    if (active) {
      f32x4 sacc[4];
#pragma unroll
      for (int n = 0; n < 4; ++n) sacc[n] = (f32x4){0.f, 0.f, 0.f, 0.f};
      __builtin_amdgcn_s_setprio(1);
#pragma unroll
      for (int n = 0; n < 4; ++n)
#pragma unroll
        for (int c = 0; c < 4; ++c) {
          f16x8 kf = *(const f16x8*)&sKh[(n * 16 + l16) * 136 + c * 32 + quad * 8];
          sacc[n] = __builtin_amdgcn_mfma_f32_16x16x32_f16(kf, qf[c], sacc[n], 0, 0, 0);
        }
      __builtin_amdgcn_s_setprio(0);

      // thread's q-row: qi = qr0 + l16; score k = kt*64 + n*16 + quad*4 + r
      const int qi = qr0 + l16;
      const int kb = kt * 64 + quad * 4;
      float pm[4][4];
      float rmax = -INFINITY;
#pragma unroll
      for (int n = 0; n < 4; ++n)
#pragma unroll
        for (int r = 0; r < 4; ++r) {
          float sc = sacc[n][r];
          if (kb + n * 16 + r > qi) sc = -INFINITY;
          pm[n][r] = sc;
          rmax = fmaxf(rmax, sc);
        }
      rmax = fmaxf(rmax, __shfl_xor(rmax, 16, 64));
      rmax = fmaxf(rmax, __shfl_xor(rmax, 32, 64));

      const float mnew = fmaxf(m_r, rmax);
      const float alpha = __expf(m_r - mnew);
      m_r = mnew;
      l_r *= alpha;
      float rsum = 0.f;
#pragma unroll
      for (int n = 0; n < 4; ++n)
#pragma unroll
        for (int r = 0; r < 4; ++r) {
          float pv = __expf(pm[n][r] - m_r);
          pm[n][r] = pv;
          rsum += pv;
        }
      rsum += __shfl_xor(rsum, 16, 64);
      rsum += __shfl_xor(rsum, 32, 64);
      l_r += rsum;

      // redistribute alpha to PV C-layout rows (quad*4 + r)
      float apv[4];
#pragma unroll
      for (int r = 0; r < 4; ++r)
        apv[r] = __shfl(alpha, (lane & 48) | (quad * 4 + r), 64);
#pragma unroll
      for (int d = 0; d < 8; ++d)
#pragma unroll
        for (int r = 0; r < 4; ++r) oacc[d][r] *= apv[r];

      // P -> per-wave LDS (A-layout row = q-local l16), packed ushort4
#pragma unroll
      for (int n = 0; n < 4; ++n) {
        ushort4 pk;
        pk.x = f2h(pm[n][0]);
        pk.y = f2h(pm[n][1]);
        pk.z = f2h(pm[n][2]);
        pk.w = f2h(pm[n][3]);
        *(ushort4*)&sP[l16 * 68 + n * 16 + quad * 4] = pk;
      }

      // O += P.V
      __builtin_amdgcn_s_setprio(1);
#pragma unroll
      for (int c = 0; c < 2; ++c) {
        f16x8 pf = *(const f16x8*)&sP[l16 * 68 + c * 32 + quad * 8];
#pragma unroll
        for (int d = 0; d < 8; ++d) {
          f16x8 vf = *(const f16x8*)&sVt[(d * 16 + l16) * 72 + c * 32 + quad * 8];
          oacc[d] = __builtin_amdgcn_mfma_f32_16x16x32_f16(pf, vf, oacc[d], 0, 0, 0);
        }
      }
      __builtin_amdgcn_s_setprio(0);
    }
  }

  const float invl = 1.f / l_r;
  float ipv[4];
#pragma unroll
  for (int r = 0; r < 4; ++r)
    ipv[r] = __shfl(invl, (lane & 48) | (quad * 4 + r), 64);
#pragma unroll
  for (int d = 0; d < 8; ++d)
#pragma unroll
    for (int r = 0; r < 4; ++r) {
      int row = qr0 + quad * 4 + r;
      Ch[bhbase + (size_t)row * DMODEL + d * 16 + l16] = f2h(oacc[d][r] * ipv[r]);
    }
}

extern "C" void kernel_launch(void* const* d_in, const int* in_sizes, int n_in,
                              void* d_out, int out_size, void* d_ws, size_t ws_size,
                              hipStream_t stream) {
  const float* x    = (const float*)d_in[0];
  const float* Wq   = (const float*)d_in[1];
  const float* Wk   = (const float*)d_in[2];
  const float* Wv   = (const float*)d_in[3];
  const float* Wo   = (const float*)d_in[4];
  const float* cosT = (const float*)d_in[5];
  const float* sinT = (const float*)d_in[6];
  float* out = (float*)d_out;

  const size_t NX = 8388608;   // 2*2048*2048
  const size_t NW = 4194304;   // 2048*2048
  u16* p = (u16*)d_ws;
  u16* xh  = p; p += NX;  u16* xl  = p; p += NX;
  u16* Wqh = p; p += NW;  u16* Wql = p; p += NW;
  u16* Wkh = p; p += NW;  u16* Wkl = p; p += NW;
  u16* Wvh = p; p += NW;  u16* Woh = p; p += NW;
  u16* qh  = p; p += NX;  u16* kh  = p; p += NX;
  u16* vt  = p; p += NX;
  u16* ch  = p; p += NX;
  // ~150 MiB of d_ws

  split_all<<<98304, 256, 0, stream>>>(x, Wq, Wk, Wv, Wo,
                                       xh, xl, Wqh, Wql, Wkh, Wkl, Wvh, Woh);

  q_kernel<<<dim3(16, 32), 256, 0, stream>>>(xh, xl, Wqh, Wql, cosT, sinT, qh);
  k_kernel<<<dim3(16, 32), 256, 0, stream>>>(xh, xl, Wkh, Wkl, cosT, sinT, kh);
  v_kernel<<<dim3(16, 32), 256, 0, stream>>>(xh, Wvh, vt);

  attn_kernel<<<dim3(16, 32), 512, 0, stream>>>(qh, kh, vt, ch);

  out_kernel<<<dim3(16, 32), 256, 0, stream>>>(ch, Woh, out);
}